// Round 15
// baseline (948.185 us; speedup 1.0000x reference)
//
#include <hip/hip_runtime.h>
#include <hip/hip_bf16.h>
#include <cmath>

// ---------------------------------------------------------------------------
// SelectiveMagnoViT forward. Round 14: R13 (best 926us) with
//  - gather folded into the embed GEMM's A-staging (no selp buffer)
//  - residual h prefetched at attnproj entry (latency hidden under attn)
// ---------------------------------------------------------------------------

#define Bsz   64
#define NPATCH 576
#define KSEL  144
#define SEQ   145
#define DIM   192
#define HIDN  768

typedef __bf16 bf16x8 __attribute__((ext_vector_type(8)));
typedef float  f32x4  __attribute__((ext_vector_type(4)));

// ---------------- patch scores: wave = patch, lane reads float4 -------------
__global__ __launch_bounds__(256) void scores_kernel(const float* __restrict__ line,
                                                     float* __restrict__ scores)
{
    int gp = blockIdx.x * 4 + (threadIdx.x >> 6);   // global patch id
    int lane = threadIdx.x & 63;
    int b = gp / NPATCH, p = gp % NPATCH;
    int gy = p / 24, gx = p % 24;
    const float* base = &line[((size_t)b * 384 + gy * 16 + (lane >> 2)) * 384
                              + gx * 16 + (lane & 3) * 4];
    float4 v = *reinterpret_cast<const float4*>(base);
    float s = v.x + v.y + v.z + v.w;
    for (int off = 32; off; off >>= 1) s += __shfl_xor(s, off);
    if (lane == 0) scores[gp] = s * (1.f / 256.f);
}

// ---------------- exact top-k via rank scatter (jax order, no serial) -------
__global__ __launch_bounds__(256) void topk_kernel(const float* __restrict__ scores,
                                                   int* __restrict__ idx)
{
    int b = blockIdx.x;
    __shared__ float s[NPATCH];
    for (int i = threadIdx.x; i < NPATCH; i += 256) s[i] = scores[b * NPATCH + i];
    __syncthreads();
    for (int i = threadIdx.x; i < NPATCH; i += 256) {
        float si = s[i];
        int cnt = 0;
        for (int j = 0; j < NPATCH; ++j) {
            float sj = s[j];
            cnt += (sj > si) || (sj == si && j < i);
        }
        if (cnt < KSEL) idx[b * KSEL + cnt] = i;
    }
}

// ---------------- fused weight prep: 4 transposes + conv convert ------------
__global__ __launch_bounds__(256) void prep_weights(
    const float* __restrict__ qkv_w, const float* __restrict__ proj_w,
    const float* __restrict__ fc1_w, const float* __restrict__ fc2_w,
    const float* __restrict__ conv_w,
    __hip_bfloat16* __restrict__ wt_qkv, __hip_bfloat16* __restrict__ wt_proj,
    __hip_bfloat16* __restrict__ wt_fc1, __hip_bfloat16* __restrict__ wt_fc2,
    __hip_bfloat16* __restrict__ convT)
{
    __shared__ float t[32][33];
    int bid = blockIdx.x;
    const float* src;
    __hip_bfloat16* dst;
    int R, C, rem;
    if (bid < 1296)      { src = qkv_w;  dst = wt_qkv;  R = 192; C = 576; rem = bid; }
    else if (bid < 1728) { src = proj_w; dst = wt_proj; R = 192; C = 192; rem = bid - 1296; }
    else if (bid < 3456) { src = fc1_w;  dst = wt_fc1;  R = 192; C = 768; rem = bid - 1728; }
    else if (bid < 5184) { src = fc2_w;  dst = wt_fc2;  R = 768; C = 192; rem = bid - 3456; }
    else {
        int i = (bid - 5184) * 1024 + threadIdx.x * 4;   // 144 blocks x 1024
        float4 v = *reinterpret_cast<const float4*>(&conv_w[i]);
        __hip_bfloat16 o[4] = {__float2bfloat16(v.x), __float2bfloat16(v.y),
                               __float2bfloat16(v.z), __float2bfloat16(v.w)};
        *reinterpret_cast<uint2*>(&convT[i]) = *reinterpret_cast<uint2*>(o);
        return;
    }
    int TR = R / 32, TC = C / 32;
    int l = rem / (TR * TC), r2 = rem % (TR * TC);
    int r0 = (r2 / TC) * 32, c0 = (r2 % TC) * 32;
    size_t lo = (size_t)l * R * C;
    int tx = threadIdx.x & 31, ty = threadIdx.x >> 5;
#pragma unroll
    for (int i = 0; i < 32; i += 8)
        t[ty + i][tx] = src[lo + (size_t)(r0 + ty + i) * C + c0 + tx];
    __syncthreads();
#pragma unroll
    for (int i = 0; i < 32; i += 8)
        dst[lo + (size_t)(c0 + ty + i) * R + r0 + tx] = __float2bfloat16(t[tx][ty + i]);
}

// ---------------- cls token init --------------------------------------------
__global__ void cls_kernel(const float* __restrict__ cls, const float* __restrict__ pos,
                           float* __restrict__ h)
{
    int b = blockIdx.x, t = threadIdx.x;      // 192 threads
    h[(size_t)b * SEQ * DIM + t] = cls[t] + pos[t];
}

// ---------------- LayerNorm over D=192 -> bf16 out (layer-0 ln1 only) -------
__global__ __launch_bounds__(256) void ln_kernel(const float* __restrict__ x,
                                                 const float* __restrict__ s,
                                                 const float* __restrict__ bia,
                                                 __hip_bfloat16* __restrict__ y, int ntok)
{
    int w = threadIdx.x >> 6, lane = threadIdx.x & 63;
    int tok = blockIdx.x * 4 + w;
    if (tok >= ntok) return;
    const float* xp = &x[(size_t)tok * DIM];
    float x0 = xp[lane], x1 = xp[lane + 64], x2 = xp[lane + 128];
    float sum = x0 + x1 + x2;
    for (int off = 32; off; off >>= 1) sum += __shfl_xor(sum, off);
    float mean = sum * (1.f / 192.f);
    float d0 = x0 - mean, d1 = x1 - mean, d2 = x2 - mean;
    float vs = d0 * d0 + d1 * d1 + d2 * d2;
    for (int off = 32; off; off >>= 1) vs += __shfl_xor(vs, off);
    float rs = rsqrtf(vs * (1.f / 192.f) + 1e-6f);
    __hip_bfloat16* yp = &y[(size_t)tok * DIM];
    yp[lane]       = __float2bfloat16(d0 * rs * s[lane]       + bia[lane]);
    yp[lane + 64]  = __float2bfloat16(d1 * rs * s[lane + 64]  + bia[lane + 64]);
    yp[lane + 128] = __float2bfloat16(d2 * rs * s[lane + 128] + bia[lane + 128]);
}

// ---------------- embed GEMM with in-staging gather -------------------------
// A rows = selected patches read directly from magno (f32 -> bf16 in staging).
// Grid (3, 144): 64 rows x 64 cols, K = 768.
__global__ __launch_bounds__(256) void gemm_embed(const float* __restrict__ magno,
                                                  const int* __restrict__ idx,
                                                  const __hip_bfloat16* __restrict__ Wt,
                                                  const float* __restrict__ bias,
                                                  float* __restrict__ h,
                                                  const float* __restrict__ pos)
{
    __shared__ __align__(16) char As[8192];
    __shared__ __align__(16) char Bs[8192];
    __shared__ int pgy[64], pgx[64], pb[64], ppi[64];
    const int tid = threadIdx.x;
    const int lane = tid & 63, wid = tid >> 6;
    const int wr = wid >> 1, wc = wid & 1;
    const int lr = lane & 15, lk = lane >> 4;
    const int m0 = blockIdx.y * 64, n0 = blockIdx.x * 64;
    const int K = 768;
    f32x4 acc[2][2] = {};

    if (tid < 64) {
        int row = m0 + tid;
        int pi = idx[row];
        ppi[tid] = pi;
        pb[tid] = row / KSEL;
        pgy[tid] = pi / 24;
        pgx[tid] = pi % 24;
    }
    __syncthreads();

    for (int k0 = 0; k0 < K; k0 += 64) {
#pragma unroll
        for (int it = 0; it < 2; ++it) {
            int chunk = it * 256 + tid;
            int r = chunk >> 3, g = chunk & 7;
            int loff = r * 128 + ((g ^ (r & 7)) * 16);
            // gather A: k = k0+g*8 -> (c, py, px0); 8 consecutive px
            int k = k0 + g * 8;
            int c = k >> 8, py = (k >> 4) & 15, px0 = k & 15;
            const float* src = &magno[((size_t)pb[r] * 3 + c) * 147456
                                      + (size_t)(pgy[r] * 16 + py) * 384
                                      + pgx[r] * 16 + px0];
            float4 v0 = *reinterpret_cast<const float4*>(src);
            float4 v1 = *reinterpret_cast<const float4*>(src + 4);
            __hip_bfloat16 o[8] = {
                __float2bfloat16(v0.x), __float2bfloat16(v0.y),
                __float2bfloat16(v0.z), __float2bfloat16(v0.w),
                __float2bfloat16(v1.x), __float2bfloat16(v1.y),
                __float2bfloat16(v1.z), __float2bfloat16(v1.w)};
            *reinterpret_cast<uint4*>(As + loff) = *reinterpret_cast<uint4*>(o);
            *reinterpret_cast<uint4*>(Bs + loff) =
                *reinterpret_cast<const uint4*>(&Wt[(size_t)(n0 + r) * K + k0 + g * 8]);
        }
        __syncthreads();
#pragma unroll
        for (int kc = 0; kc < 2; ++kc) {
            int g = kc * 4 + lk;
            bf16x8 af[2], bfr[2];
#pragma unroll
            for (int mi = 0; mi < 2; ++mi) {
                int r = wr * 32 + mi * 16 + lr;
                af[mi] = *reinterpret_cast<const bf16x8*>(As + r * 128 + ((g ^ (r & 7)) * 16));
            }
#pragma unroll
            for (int ni = 0; ni < 2; ++ni) {
                int r = wc * 32 + ni * 16 + lr;
                bfr[ni] = *reinterpret_cast<const bf16x8*>(Bs + r * 128 + ((g ^ (r & 7)) * 16));
            }
#pragma unroll
            for (int mi = 0; mi < 2; ++mi)
#pragma unroll
                for (int ni = 0; ni < 2; ++ni)
                    acc[mi][ni] = __builtin_amdgcn_mfma_f32_16x16x32_bf16(
                        af[mi], bfr[ni], acc[mi][ni], 0, 0, 0);
        }
        __syncthreads();
    }

#pragma unroll
    for (int mi = 0; mi < 2; ++mi)
#pragma unroll
    for (int ni = 0; ni < 2; ++ni)
#pragma unroll
    for (int j = 0; j < 4; ++j) {
        int rr = wr * 32 + mi * 16 + (lane >> 4) * 4 + j;   // row within tile
        int row = m0 + rr;
        int col = n0 + wc * 32 + ni * 16 + (lane & 15);
        float v = acc[mi][ni][j] + bias[col];
        int bb2 = pb[rr], ss = row - bb2 * KSEL;
        v += pos[(size_t)(1 + ppi[rr]) * DIM + col];
        h[((size_t)bb2 * SEQ + 1 + ss) * DIM + col] = v;
    }
}

// ---------------- fc1 GEMM + gelu (MODE 2 of old gemm_bf16) -----------------
__global__ __launch_bounds__(256) void gemm_fc1(const __hip_bfloat16* __restrict__ A,
                                                const __hip_bfloat16* __restrict__ Wt,
                                                const float* __restrict__ bias,
                                                __hip_bfloat16* __restrict__ Cout)
{
    __shared__ __align__(16) char As[8192];
    __shared__ __align__(16) char Bs[8192];
    const int tid = threadIdx.x;
    const int lane = tid & 63, wid = tid >> 6;
    const int wr = wid >> 1, wc = wid & 1;
    const int lr = lane & 15, lk = lane >> 4;
    const int m0 = blockIdx.y * 64, n0 = blockIdx.x * 64;
    const int K = DIM, N = HIDN;
    f32x4 acc[2][2] = {};

    for (int k0 = 0; k0 < K; k0 += 64) {
#pragma unroll
        for (int it = 0; it < 2; ++it) {
            int chunk = it * 256 + tid;
            int r = chunk >> 3, g = chunk & 7;
            int loff = r * 128 + ((g ^ (r & 7)) * 16);
            *reinterpret_cast<uint4*>(As + loff) =
                *reinterpret_cast<const uint4*>(&A[(size_t)(m0 + r) * K + k0 + g * 8]);
            *reinterpret_cast<uint4*>(Bs + loff) =
                *reinterpret_cast<const uint4*>(&Wt[(size_t)(n0 + r) * K + k0 + g * 8]);
        }
        __syncthreads();
#pragma unroll
        for (int kc = 0; kc < 2; ++kc) {
            int g = kc * 4 + lk;
            bf16x8 af[2], bfr[2];
#pragma unroll
            for (int mi = 0; mi < 2; ++mi) {
                int r = wr * 32 + mi * 16 + lr;
                af[mi] = *reinterpret_cast<const bf16x8*>(As + r * 128 + ((g ^ (r & 7)) * 16));
            }
#pragma unroll
            for (int ni = 0; ni < 2; ++ni) {
                int r = wc * 32 + ni * 16 + lr;
                bfr[ni] = *reinterpret_cast<const bf16x8*>(Bs + r * 128 + ((g ^ (r & 7)) * 16));
            }
#pragma unroll
            for (int mi = 0; mi < 2; ++mi)
#pragma unroll
                for (int ni = 0; ni < 2; ++ni)
                    acc[mi][ni] = __builtin_amdgcn_mfma_f32_16x16x32_bf16(
                        af[mi], bfr[ni], acc[mi][ni], 0, 0, 0);
        }
        __syncthreads();
    }

#pragma unroll
    for (int mi = 0; mi < 2; ++mi)
#pragma unroll
    for (int ni = 0; ni < 2; ++ni)
#pragma unroll
    for (int j = 0; j < 4; ++j) {
        int row = m0 + wr * 32 + mi * 16 + (lane >> 4) * 4 + j;
        int col = n0 + wc * 32 + ni * 16 + (lane & 15);
        float v = acc[mi][ni][j] + bias[col];
        Cout[(size_t)row * N + col] =
            __float2bfloat16(0.5f * v * (1.f + erff(v * 0.70710678118654752f)));
    }
}

// ---------------- qkv GEMM: N=576; cols<384 -> qk; cols>=384 -> Vt^T --------
__global__ __launch_bounds__(256) void gemm_qkv(const __hip_bfloat16* __restrict__ A,
                                                const __hip_bfloat16* __restrict__ Wt,
                                                const float* __restrict__ bias,
                                                __hip_bfloat16* __restrict__ qk,
                                                __hip_bfloat16* __restrict__ Vt)
{
    __shared__ __align__(16) char As[8192];
    __shared__ __align__(16) char Bs[8192];
    const int tid = threadIdx.x;
    const int lane = tid & 63, wid = tid >> 6;
    const int wr = wid >> 1, wc = wid & 1;
    const int lr = lane & 15, lk = lane >> 4;
    const int m0 = blockIdx.y * 64, n0 = blockIdx.x * 64;
    const int K = DIM;
    f32x4 acc[2][2] = {};

    for (int k0 = 0; k0 < K; k0 += 64) {
#pragma unroll
        for (int it = 0; it < 2; ++it) {
            int chunk = it * 256 + tid;
            int r = chunk >> 3, g = chunk & 7;
            int loff = r * 128 + ((g ^ (r & 7)) * 16);
            *reinterpret_cast<uint4*>(As + loff) =
                *reinterpret_cast<const uint4*>(&A[(size_t)(m0 + r) * K + k0 + g * 8]);
            *reinterpret_cast<uint4*>(Bs + loff) =
                *reinterpret_cast<const uint4*>(&Wt[(size_t)(n0 + r) * K + k0 + g * 8]);
        }
        __syncthreads();
#pragma unroll
        for (int kc = 0; kc < 2; ++kc) {
            int g = kc * 4 + lk;
            bf16x8 af[2], bfr[2];
#pragma unroll
            for (int mi = 0; mi < 2; ++mi) {
                int r = wr * 32 + mi * 16 + lr;
                af[mi] = *reinterpret_cast<const bf16x8*>(As + r * 128 + ((g ^ (r & 7)) * 16));
            }
#pragma unroll
            for (int ni = 0; ni < 2; ++ni) {
                int r = wc * 32 + ni * 16 + lr;
                bfr[ni] = *reinterpret_cast<const bf16x8*>(Bs + r * 128 + ((g ^ (r & 7)) * 16));
            }
#pragma unroll
            for (int mi = 0; mi < 2; ++mi)
#pragma unroll
                for (int ni = 0; ni < 2; ++ni)
                    acc[mi][ni] = __builtin_amdgcn_mfma_f32_16x16x32_bf16(
                        af[mi], bfr[ni], acc[mi][ni], 0, 0, 0);
        }
        __syncthreads();
    }

#pragma unroll
    for (int mi = 0; mi < 2; ++mi)
#pragma unroll
    for (int ni = 0; ni < 2; ++ni)
#pragma unroll
    for (int j = 0; j < 4; ++j) {
        int row = m0 + wr * 32 + mi * 16 + (lane >> 4) * 4 + j;
        int col = n0 + wc * 32 + ni * 16 + (lane & 15);
        float v = acc[mi][ni][j] + bias[col];
        if (col < 384) {
            qk[(size_t)row * 384 + col] = __float2bfloat16(v);
        } else {
            int c = col - 384;
            int b = row / SEQ, s = row - b * SEQ;
            Vt[((size_t)(b * 3 + (c >> 6)) * 64 + (c & 63)) * 160 + s] = __float2bfloat16(v);
        }
    }
}

// ---------------- fused attention + proj + bias + residual + ln2 ------------
// h residual tile prefetched at kernel entry (hidden under attn phases).
__global__ __launch_bounds__(256) void attnproj_kernel(const __hip_bfloat16* __restrict__ qk,
                                                       const __hip_bfloat16* __restrict__ Vt,
                                                       const __hip_bfloat16* __restrict__ Wp,
                                                       const float* __restrict__ pbias,
                                                       float* __restrict__ h,
                                                       const float* __restrict__ ls,
                                                       const float* __restrict__ lb,
                                                       __hip_bfloat16* __restrict__ y)
{
    const int b = blockIdx.y, qt = blockIdx.x;
    const int tid = threadIdx.x;
    const int w = tid >> 6, lane = tid & 63;
    const int lr = lane & 15, lg = lane >> 4;
    __shared__ __hip_bfloat16 Ps[3][32][168];
    __shared__ __hip_bfloat16 Ot[32][200];
    __shared__ float redsum[4][32];
    __shared__ float redsq[4][32];

    const size_t qbase = (size_t)b * SEQ * 384;
    const int q0 = qt * 32;

    // ---- prefetch residual h tile (consumed in proj epilogue) ----
    float hres[2][3][4];
#pragma unroll
    for (int mi = 0; mi < 2; ++mi)
#pragma unroll
    for (int nf = 0; nf < 3; ++nf) {
        int col = w * 48 + nf * 16 + lr;
#pragma unroll
        for (int j = 0; j < 4; ++j) {
            int q = q0 + mi * 16 + lg * 4 + j;
            hres[mi][nf][j] = (q < SEQ) ? h[((size_t)b * SEQ + q) * DIM + col] : 0.f;
        }
    }

    if (w < 3) {
        const int hh = w;
        bf16x8 aq[2][2];
#pragma unroll
        for (int mi = 0; mi < 2; ++mi)
#pragma unroll
            for (int ks = 0; ks < 2; ++ks)
                aq[mi][ks] = *reinterpret_cast<const bf16x8*>(
                    &qk[qbase + (size_t)(q0 + mi * 16 + lr) * 384 + hh * 64 + ks * 32 + lg * 8]);
        f32x4 sc[2][10];
#pragma unroll
        for (int mi = 0; mi < 2; ++mi)
#pragma unroll
            for (int nf = 0; nf < 10; ++nf) sc[mi][nf] = (f32x4){0.f, 0.f, 0.f, 0.f};
#pragma unroll
        for (int nf = 0; nf < 10; ++nf) {
            int key = nf * 16 + lr;
#pragma unroll
            for (int ks = 0; ks < 2; ++ks) {
                bf16x8 bk = *reinterpret_cast<const bf16x8*>(
                    &qk[qbase + (size_t)key * 384 + 192 + hh * 64 + ks * 32 + lg * 8]);
#pragma unroll
                for (int mi = 0; mi < 2; ++mi)
                    sc[mi][nf] = __builtin_amdgcn_mfma_f32_16x16x32_bf16(
                        aq[mi][ks], bk, sc[mi][nf], 0, 0, 0);
            }
        }
#pragma unroll
        for (int mi = 0; mi < 2; ++mi) {
            float mx[4] = {-1e30f, -1e30f, -1e30f, -1e30f};
#pragma unroll
            for (int nf = 0; nf < 10; ++nf) {
                bool valid = nf * 16 + lr < SEQ;
#pragma unroll
                for (int j = 0; j < 4; ++j) {
                    float v = valid ? sc[mi][nf][j] * 0.125f : -1e30f;
                    sc[mi][nf][j] = v;
                    mx[j] = fmaxf(mx[j], v);
                }
            }
#pragma unroll
            for (int j = 0; j < 4; ++j)
                for (int off = 1; off < 16; off <<= 1)
                    mx[j] = fmaxf(mx[j], __shfl_xor(mx[j], off));
            float sm[4] = {0.f, 0.f, 0.f, 0.f};
#pragma unroll
            for (int nf = 0; nf < 10; ++nf)
#pragma unroll
                for (int j = 0; j < 4; ++j) {
                    float p = __expf(sc[mi][nf][j] - mx[j]);
                    sc[mi][nf][j] = p;
                    sm[j] += p;
                }
#pragma unroll
            for (int j = 0; j < 4; ++j) {
                for (int off = 1; off < 16; off <<= 1) sm[j] += __shfl_xor(sm[j], off);
                sm[j] = 1.f / sm[j];
            }
#pragma unroll
            for (int nf = 0; nf < 10; ++nf) {
                int key = nf * 16 + lr;
#pragma unroll
                for (int j = 0; j < 4; ++j)
                    Ps[hh][mi * 16 + lg * 4 + j][key] = __float2bfloat16(sc[mi][nf][j] * sm[j]);
            }
        }
        const __hip_bfloat16* vtb = &Vt[(size_t)(b * 3 + hh) * 64 * 160];
        f32x4 oacc[2][4];
#pragma unroll
        for (int mi = 0; mi < 2; ++mi)
#pragma unroll
            for (int nf = 0; nf < 4; ++nf) oacc[mi][nf] = (f32x4){0.f, 0.f, 0.f, 0.f};
#pragma unroll
        for (int ks = 0; ks < 5; ++ks) {
            bf16x8 ap[2];
            ap[0] = *reinterpret_cast<const bf16x8*>(&Ps[hh][lr][ks * 32 + lg * 8]);
            ap[1] = *reinterpret_cast<const bf16x8*>(&Ps[hh][16 + lr][ks * 32 + lg * 8]);
#pragma unroll
            for (int nf = 0; nf < 4; ++nf) {
                bf16x8 bv = *reinterpret_cast<const bf16x8*>(
                    &vtb[(size_t)(nf * 16 + lr) * 160 + ks * 32 + lg * 8]);
#pragma unroll
                for (int mi = 0; mi < 2; ++mi)
                    oacc[mi][nf] = __builtin_amdgcn_mfma_f32_16x16x32_bf16(
                        ap[mi], bv, oacc[mi][nf], 0, 0, 0);
            }
        }
#pragma unroll
        for (int mi = 0; mi < 2; ++mi)
#pragma unroll
            for (int nf = 0; nf < 4; ++nf)
#pragma unroll
                for (int j = 0; j < 4; ++j)
                    Ot[mi * 16 + lg * 4 + j][hh * 64 + nf * 16 + lr] =
                        __float2bfloat16(oacc[mi][nf][j]);
    }
    __syncthreads();

    f32x4 pacc[2][3];
#pragma unroll
    for (int mi = 0; mi < 2; ++mi)
#pragma unroll
        for (int nf = 0; nf < 3; ++nf) pacc[mi][nf] = (f32x4){0.f, 0.f, 0.f, 0.f};
#pragma unroll
    for (int kk = 0; kk < 6; ++kk) {
        bf16x8 af[2];
        af[0] = *reinterpret_cast<const bf16x8*>(&Ot[lr][kk * 32 + lg * 8]);
        af[1] = *reinterpret_cast<const bf16x8*>(&Ot[16 + lr][kk * 32 + lg * 8]);
#pragma unroll
        for (int nf = 0; nf < 3; ++nf) {
            int ncol = w * 48 + nf * 16 + lr;
            bf16x8 bw = *reinterpret_cast<const bf16x8*>(&Wp[(size_t)ncol * 192 + kk * 32 + lg * 8]);
#pragma unroll
            for (int mi = 0; mi < 2; ++mi)
                pacc[mi][nf] = __builtin_amdgcn_mfma_f32_16x16x32_bf16(
                    af[mi], bw, pacc[mi][nf], 0, 0, 0);
        }
    }
    float v[2][3][4];
    float psum[2][4] = {}, psq[2][4] = {};
#pragma unroll
    for (int mi = 0; mi < 2; ++mi)
#pragma unroll
    for (int nf = 0; nf < 3; ++nf) {
        int col = w * 48 + nf * 16 + lr;
        float bcol = pbias[col];
#pragma unroll
        for (int j = 0; j < 4; ++j) {
            float t = pacc[mi][nf][j] + bcol + hres[mi][nf][j];
            v[mi][nf][j] = t;
            psum[mi][j] += t;
            psq[mi][j] += t * t;
        }
    }
#pragma unroll
    for (int mi = 0; mi < 2; ++mi)
#pragma unroll
        for (int j = 0; j < 4; ++j) {
            for (int off = 1; off < 16; off <<= 1) {
                psum[mi][j] += __shfl_xor(psum[mi][j], off);
                psq[mi][j]  += __shfl_xor(psq[mi][j], off);
            }
            redsum[w][mi * 16 + lg * 4 + j] = psum[mi][j];
            redsq[w][mi * 16 + lg * 4 + j]  = psq[mi][j];
        }
    __syncthreads();
#pragma unroll
    for (int mi = 0; mi < 2; ++mi) {
#pragma unroll
        for (int j = 0; j < 4; ++j) {
            int r = mi * 16 + lg * 4 + j;
            int q = q0 + r;
            if (q >= SEQ) continue;
            float tsum = redsum[0][r] + redsum[1][r] + redsum[2][r] + redsum[3][r];
            float tsq  = redsq[0][r]  + redsq[1][r]  + redsq[2][r]  + redsq[3][r];
            float mean = tsum * (1.f / 192.f);
            float var  = tsq * (1.f / 192.f) - mean * mean;
            float rs = rsqrtf(var + 1e-6f);
#pragma unroll
            for (int nf = 0; nf < 3; ++nf) {
                int col = w * 48 + nf * 16 + lr;
                float t = v[mi][nf][j];
                h[((size_t)b * SEQ + q) * DIM + col] = t;
                y[((size_t)b * SEQ + q) * DIM + col] =
                    __float2bfloat16((t - mean) * rs * ls[col] + lb[col]);
            }
        }
    }
}

// ---------------- fc2 + bias + residual + LN (round-5 version) --------------
template <bool DO_LN>
__global__ __launch_bounds__(256) void gemm_res_ln(const __hip_bfloat16* __restrict__ A,
                                                   const __hip_bfloat16* __restrict__ Wt,
                                                   const float* __restrict__ bias,
                                                   float* __restrict__ h,
                                                   const float* __restrict__ ls,
                                                   const float* __restrict__ lb,
                                                   __hip_bfloat16* __restrict__ y,
                                                   int K)
{
    __shared__ __align__(16) char As[8192];    // 64 x 64 bf16 swizzled
    __shared__ __align__(16) char Bs[24576];   // 192 x 64 bf16 swizzled
    const int tid = threadIdx.x;
    const int lane = tid & 63, w = tid >> 6;
    const int lr = lane & 15, lg = lane >> 4;
    const int m0 = blockIdx.x * 64;
    f32x4 acc[12] = {};

    for (int k0 = 0; k0 < K; k0 += 64) {
        {
            int chunk = tid;
#pragma unroll
            for (int it = 0; it < 2; ++it, chunk += 256) {
                int r = chunk >> 3, g = chunk & 7;
                *reinterpret_cast<uint4*>(As + r * 128 + ((g ^ (r & 7)) * 16)) =
                    *reinterpret_cast<const uint4*>(&A[(size_t)(m0 + r) * K + k0 + g * 8]);
            }
        }
        {
            int chunk = tid;
#pragma unroll
            for (int it = 0; it < 6; ++it, chunk += 256) {
                int r = chunk >> 3, g = chunk & 7;
                *reinterpret_cast<uint4*>(Bs + r * 128 + ((g ^ (r & 7)) * 16)) =
                    *reinterpret_cast<const uint4*>(&Wt[(size_t)r * K + k0 + g * 8]);
            }
        }
        __syncthreads();
#pragma unroll
        for (int kc = 0; kc < 2; ++kc) {
            int g = kc * 4 + lg;
            int ar = w * 16 + lr;
            bf16x8 af = *reinterpret_cast<const bf16x8*>(As + ar * 128 + ((g ^ (ar & 7)) * 16));
#pragma unroll
            for (int nf = 0; nf < 12; ++nf) {
                int br = nf * 16 + lr;
                bf16x8 bfv = *reinterpret_cast<const bf16x8*>(Bs + br * 128 + ((g ^ (br & 7)) * 16));
                acc[nf] = __builtin_amdgcn_mfma_f32_16x16x32_bf16(af, bfv, acc[nf], 0, 0, 0);
            }
        }
        __syncthreads();
    }

    float v[12][4];
    float sum[4] = {0.f, 0.f, 0.f, 0.f};
#pragma unroll
    for (int nf = 0; nf < 12; ++nf) {
        int col = nf * 16 + lr;
#pragma unroll
        for (int j = 0; j < 4; ++j) {
            int row = m0 + w * 16 + lg * 4 + j;
            float t = acc[nf][j] + bias[col] + h[(size_t)row * DIM + col];
            v[nf][j] = t;
            h[(size_t)row * DIM + col] = t;
            sum[j] += t;
        }
    }
    if (DO_LN) {
#pragma unroll
        for (int j = 0; j < 4; ++j)
            for (int off = 1; off < 16; off <<= 1) sum[j] += __shfl_xor(sum[j], off);
        float mean[4], sq[4] = {0.f, 0.f, 0.f, 0.f};
#pragma unroll
        for (int j = 0; j < 4; ++j) mean[j] = sum[j] * (1.f / 192.f);
#pragma unroll
        for (int nf = 0; nf < 12; ++nf)
#pragma unroll
            for (int j = 0; j < 4; ++j) {
                float d = v[nf][j] - mean[j];
                sq[j] += d * d;
            }
#pragma unroll
        for (int j = 0; j < 4; ++j) {
            for (int off = 1; off < 16; off <<= 1) sq[j] += __shfl_xor(sq[j], off);
            sq[j] = rsqrtf(sq[j] * (1.f / 192.f) + 1e-6f);
        }
#pragma unroll
        for (int nf = 0; nf < 12; ++nf) {
            int col = nf * 16 + lr;
            float sc = ls[col], bc = lb[col];
#pragma unroll
            for (int j = 0; j < 4; ++j) {
                int row = m0 + w * 16 + lg * 4 + j;
                y[(size_t)row * DIM + col] =
                    __float2bfloat16((v[nf][j] - mean[j]) * sq[j] * sc + bc);
            }
        }
    }
}

// ---------------- head: final LN of cls + (64,192)@(192,1000) ---------------
__global__ __launch_bounds__(256) void head_kernel(const float* __restrict__ h,
                                                   const float* __restrict__ nfs,
                                                   const float* __restrict__ nfb,
                                                   const float* __restrict__ hw,
                                                   const float* __restrict__ hb,
                                                   float* __restrict__ out)
{
    int b = blockIdx.x, t = threadIdx.x;
    __shared__ float y[DIM];
    __shared__ float red[4];
    float x = (t < DIM) ? h[(size_t)b * SEQ * DIM + t] : 0.f;
    float sum = x;
    for (int off = 32; off; off >>= 1) sum += __shfl_xor(sum, off);
    if ((t & 63) == 0) red[t >> 6] = sum;
    __syncthreads();
    float mean = (red[0] + red[1] + red[2] + red[3]) * (1.f / 192.f);
    __syncthreads();
    float d = (t < DIM) ? (x - mean) : 0.f;
    float v = d * d;
    for (int off = 32; off; off >>= 1) v += __shfl_xor(v, off);
    if ((t & 63) == 0) red[t >> 6] = v;
    __syncthreads();
    float var = (red[0] + red[1] + red[2] + red[3]) * (1.f / 192.f);
    float rs = rsqrtf(var + 1e-6f);
    if (t < DIM) y[t] = d * rs * nfs[t] + nfb[t];
    __syncthreads();
    for (int n = t; n < 1000; n += 256) {
        float acc = hb[n];
#pragma unroll 8
        for (int k = 0; k < DIM; ++k)
            acc = fmaf(y[k], hw[(size_t)k * 1000 + n], acc);
        out[(size_t)b * 1000 + n] = acc;
    }
}

// ---------------------------------------------------------------------------
extern "C" void kernel_launch(void* const* d_in, const int* in_sizes, int n_in,
                              void* d_out, int out_size, void* d_ws, size_t ws_size,
                              hipStream_t stream)
{
    const float* magno  = (const float*)d_in[0];
    const float* line   = (const float*)d_in[1];
    const float* conv_w = (const float*)d_in[2];
    const float* conv_b = (const float*)d_in[3];
    const float* pos    = (const float*)d_in[4];
    const float* cls    = (const float*)d_in[5];
    const float* ln1_s  = (const float*)d_in[6];
    const float* ln1_b  = (const float*)d_in[7];
    const float* qkv_w  = (const float*)d_in[8];
    const float* qkv_b  = (const float*)d_in[9];
    const float* proj_w = (const float*)d_in[10];
    const float* proj_b = (const float*)d_in[11];
    const float* ln2_s  = (const float*)d_in[12];
    const float* ln2_b  = (const float*)d_in[13];
    const float* fc1_w  = (const float*)d_in[14];
    const float* fc1_b  = (const float*)d_in[15];
    const float* fc2_w  = (const float*)d_in[16];
    const float* fc2_b  = (const float*)d_in[17];
    const float* normf_s = (const float*)d_in[18];
    const float* normf_b = (const float*)d_in[19];
    const float* head_w = (const float*)d_in[20];
    const float* head_b = (const float*)d_in[21];
    float* out = (float*)d_out;
    (void)in_sizes; (void)n_in; (void)out_size; (void)ws_size;

    // workspace layout (bytes)
    char* ws = (char*)d_ws;
    int*            idx     = (int*)            (ws + 0);         //    36864 (pad)
    float*          h       = (float*)          (ws + 147456);    //  7127040
    __hip_bfloat16* y       = (__hip_bfloat16*) (ws + 7274496);   //  3563520
    __hip_bfloat16* qk      = (__hip_bfloat16*) (ws + 10838016);  //  7127040
    __hip_bfloat16* Vt      = (__hip_bfloat16*) (ws + 17965056);  //  3932160
    __hip_bfloat16* tbuf    = (__hip_bfloat16*) (ws + 21897216);  // 14254080
    __hip_bfloat16* wt_qkv  = (__hip_bfloat16*) (ws + 36151296);  //  2654208
    __hip_bfloat16* wt_proj = (__hip_bfloat16*) (ws + 38805504);  //   884736
    __hip_bfloat16* wt_fc1  = (__hip_bfloat16*) (ws + 39690240);  //  3538944
    __hip_bfloat16* wt_fc2  = (__hip_bfloat16*) (ws + 43229184);  //  3538944
    float*          scoresbuf = (float*)qk;             // alias (used before qk)
    __hip_bfloat16* convT     = y;                      // alias (used before y)

    // ---- prep: weights -> bf16 [N][K] (one kernel); zero Vt pads once ----
    hipMemsetAsync(Vt, 0, 3932160, stream);
    prep_weights<<<5328, 256, 0, stream>>>(qkv_w, proj_w, fc1_w, fc2_w, conv_w,
                                           wt_qkv, wt_proj, wt_fc1, wt_fc2, convT);

    // ---- patch selection + embed (gather fused into embed staging) ----
    scores_kernel<<<Bsz * NPATCH / 4, 256, 0, stream>>>(line, scoresbuf);
    topk_kernel<<<Bsz, 256, 0, stream>>>(scoresbuf, idx);
    cls_kernel<<<Bsz, DIM, 0, stream>>>(cls, pos, h);
    gemm_embed<<<dim3(3, 144), 256, 0, stream>>>(magno, idx, convT, conv_b, h, pos);

    const int ntok = Bsz * SEQ;              // 9280 = 145*64
    ln_kernel<<<ntok / 4, 256, 0, stream>>>(h, ln1_s, ln1_b, y, ntok);
    for (int l = 0; l < 12; ++l) {
        gemm_qkv<<<dim3(9, 145), 256, 0, stream>>>(y, wt_qkv + (size_t)l * 576 * DIM,
                                                   qkv_b + l * 576, qk, Vt);
        attnproj_kernel<<<dim3(5, Bsz), 256, 0, stream>>>(qk, Vt,
                                                          wt_proj + (size_t)l * DIM * DIM,
                                                          proj_b + l * DIM, h,
                                                          ln2_s + l * DIM, ln2_b + l * DIM, y);
        gemm_fc1<<<dim3(12, 145), 256, 0, stream>>>(y, wt_fc1 + (size_t)l * HIDN * DIM,
                                                    fc1_b + l * HIDN, tbuf);
        if (l < 11)
            gemm_res_ln<true><<<145, 256, 0, stream>>>(
                tbuf, wt_fc2 + (size_t)l * DIM * HIDN, fc2_b + l * DIM, h,
                ln1_s + (l + 1) * DIM, ln1_b + (l + 1) * DIM, y, HIDN);
        else
            gemm_res_ln<false><<<145, 256, 0, stream>>>(
                tbuf, wt_fc2 + (size_t)l * DIM * HIDN, fc2_b + l * DIM, h,
                nullptr, nullptr, y, HIDN);
    }
    head_kernel<<<Bsz, 256, 0, stream>>>(h, normf_s, normf_b, head_w, head_b, out);
}

// Round 16
// 927.851 us; speedup vs baseline: 1.0219x; 1.0219x over previous
//
#include <hip/hip_runtime.h>
#include <hip/hip_bf16.h>
#include <cmath>

// ---------------------------------------------------------------------------
// SelectiveMagnoViT forward. Round 15: exact revert to round-13 (best, 926us).
// R5 layer loop (gemm_qkv -> attnproj -> fc1 -> fc2+res+LN), fused weight
// prep, 4-patch scores blocks, separate coalesced gather.
// ---------------------------------------------------------------------------

#define Bsz   64
#define NPATCH 576
#define KSEL  144
#define SEQ   145
#define DIM   192
#define HIDN  768

typedef __bf16 bf16x8 __attribute__((ext_vector_type(8)));
typedef float  f32x4  __attribute__((ext_vector_type(4)));

// ---------------- patch scores: wave = patch, lane reads float4 -------------
__global__ __launch_bounds__(256) void scores_kernel(const float* __restrict__ line,
                                                     float* __restrict__ scores)
{
    int gp = blockIdx.x * 4 + (threadIdx.x >> 6);   // global patch id
    int lane = threadIdx.x & 63;
    int b = gp / NPATCH, p = gp % NPATCH;
    int gy = p / 24, gx = p % 24;
    const float* base = &line[((size_t)b * 384 + gy * 16 + (lane >> 2)) * 384
                              + gx * 16 + (lane & 3) * 4];
    float4 v = *reinterpret_cast<const float4*>(base);
    float s = v.x + v.y + v.z + v.w;
    for (int off = 32; off; off >>= 1) s += __shfl_xor(s, off);
    if (lane == 0) scores[gp] = s * (1.f / 256.f);
}

// ---------------- exact top-k via rank scatter (jax order, no serial) -------
__global__ __launch_bounds__(256) void topk_kernel(const float* __restrict__ scores,
                                                   int* __restrict__ idx)
{
    int b = blockIdx.x;
    __shared__ float s[NPATCH];
    for (int i = threadIdx.x; i < NPATCH; i += 256) s[i] = scores[b * NPATCH + i];
    __syncthreads();
    for (int i = threadIdx.x; i < NPATCH; i += 256) {
        float si = s[i];
        int cnt = 0;
        for (int j = 0; j < NPATCH; ++j) {
            float sj = s[j];
            cnt += (sj > si) || (sj == si && j < i);
        }
        if (cnt < KSEL) idx[b * KSEL + cnt] = i;
    }
}

// ---------------- gather selected patches into bf16 (B*144, 768) ------------
__global__ __launch_bounds__(256) void gather_kernel(const float* __restrict__ magno,
                                                     const int* __restrict__ idx,
                                                     __hip_bfloat16* __restrict__ selp)
{
    int bs = blockIdx.x;              // b*144 + s
    int b = bs / KSEL;
    int pi = idx[bs];
    int gy = pi / 24, gx = pi % 24;
    int t = threadIdx.x, py = t >> 4, px = t & 15;
    size_t src = ((size_t)b * 3 * 384 + gy * 16 + py) * 384 + gx * 16 + px;
    __hip_bfloat16* dst = &selp[(size_t)bs * 768];
#pragma unroll
    for (int c = 0; c < 3; ++c)
        dst[c * 256 + t] = __float2bfloat16(magno[src + (size_t)c * 384 * 384]);
}

// ---------------- fused weight prep: 4 transposes + conv convert ------------
// grid 5328: [0,1296) qkv  [1296,1728) proj  [1728,3456) fc1
//            [3456,5184) fc2  [5184,5328) conv convert (float4)
__global__ __launch_bounds__(256) void prep_weights(
    const float* __restrict__ qkv_w, const float* __restrict__ proj_w,
    const float* __restrict__ fc1_w, const float* __restrict__ fc2_w,
    const float* __restrict__ conv_w,
    __hip_bfloat16* __restrict__ wt_qkv, __hip_bfloat16* __restrict__ wt_proj,
    __hip_bfloat16* __restrict__ wt_fc1, __hip_bfloat16* __restrict__ wt_fc2,
    __hip_bfloat16* __restrict__ convT)
{
    __shared__ float t[32][33];
    int bid = blockIdx.x;
    const float* src;
    __hip_bfloat16* dst;
    int R, C, rem;
    if (bid < 1296)      { src = qkv_w;  dst = wt_qkv;  R = 192; C = 576; rem = bid; }
    else if (bid < 1728) { src = proj_w; dst = wt_proj; R = 192; C = 192; rem = bid - 1296; }
    else if (bid < 3456) { src = fc1_w;  dst = wt_fc1;  R = 192; C = 768; rem = bid - 1728; }
    else if (bid < 5184) { src = fc2_w;  dst = wt_fc2;  R = 768; C = 192; rem = bid - 3456; }
    else {
        int i = (bid - 5184) * 1024 + threadIdx.x * 4;   // 144 blocks x 1024
        float4 v = *reinterpret_cast<const float4*>(&conv_w[i]);
        __hip_bfloat16 o[4] = {__float2bfloat16(v.x), __float2bfloat16(v.y),
                               __float2bfloat16(v.z), __float2bfloat16(v.w)};
        *reinterpret_cast<uint2*>(&convT[i]) = *reinterpret_cast<uint2*>(o);
        return;
    }
    int TR = R / 32, TC = C / 32;
    int l = rem / (TR * TC), r2 = rem % (TR * TC);
    int r0 = (r2 / TC) * 32, c0 = (r2 % TC) * 32;
    size_t lo = (size_t)l * R * C;
    int tx = threadIdx.x & 31, ty = threadIdx.x >> 5;
#pragma unroll
    for (int i = 0; i < 32; i += 8)
        t[ty + i][tx] = src[lo + (size_t)(r0 + ty + i) * C + c0 + tx];
    __syncthreads();
#pragma unroll
    for (int i = 0; i < 32; i += 8)
        dst[lo + (size_t)(c0 + ty + i) * R + r0 + tx] = __float2bfloat16(t[tx][ty + i]);
}

// ---------------- cls token init --------------------------------------------
__global__ void cls_kernel(const float* __restrict__ cls, const float* __restrict__ pos,
                           float* __restrict__ h)
{
    int b = blockIdx.x, t = threadIdx.x;      // 192 threads
    h[(size_t)b * SEQ * DIM + t] = cls[t] + pos[t];
}

// ---------------- LayerNorm over D=192 -> bf16 out (layer-0 ln1 only) -------
__global__ __launch_bounds__(256) void ln_kernel(const float* __restrict__ x,
                                                 const float* __restrict__ s,
                                                 const float* __restrict__ bia,
                                                 __hip_bfloat16* __restrict__ y, int ntok)
{
    int w = threadIdx.x >> 6, lane = threadIdx.x & 63;
    int tok = blockIdx.x * 4 + w;
    if (tok >= ntok) return;
    const float* xp = &x[(size_t)tok * DIM];
    float x0 = xp[lane], x1 = xp[lane + 64], x2 = xp[lane + 128];
    float sum = x0 + x1 + x2;
    for (int off = 32; off; off >>= 1) sum += __shfl_xor(sum, off);
    float mean = sum * (1.f / 192.f);
    float d0 = x0 - mean, d1 = x1 - mean, d2 = x2 - mean;
    float vs = d0 * d0 + d1 * d1 + d2 * d2;
    for (int off = 32; off; off >>= 1) vs += __shfl_xor(vs, off);
    float rs = rsqrtf(vs * (1.f / 192.f) + 1e-6f);
    __hip_bfloat16* yp = &y[(size_t)tok * DIM];
    yp[lane]       = __float2bfloat16(d0 * rs * s[lane]       + bia[lane]);
    yp[lane + 64]  = __float2bfloat16(d1 * rs * s[lane + 64]  + bia[lane + 64]);
    yp[lane + 128] = __float2bfloat16(d2 * rs * s[lane + 128] + bia[lane + 128]);
}

// ---------------- bf16 MFMA GEMM: C = A(M,K)bf16 @ Wt(N,K)bf16^T + bias -----
// MODE 2: gelu -> bf16   MODE 3: patch embed -> f32 h
template <int MODE>
__global__ __launch_bounds__(256) void gemm_bf16(const __hip_bfloat16* __restrict__ A,
                                                 const __hip_bfloat16* __restrict__ Wt,
                                                 const float* __restrict__ bias,
                                                 void* __restrict__ Cout,
                                                 int M, int N, int K,
                                                 const int* __restrict__ selidx,
                                                 const float* __restrict__ pos)
{
    __shared__ __align__(16) char As[8192];   // 64 rows x 64 bf16 (swizzled)
    __shared__ __align__(16) char Bs[8192];
    const int tid = threadIdx.x;
    const int lane = tid & 63, wid = tid >> 6;
    const int wr = wid >> 1, wc = wid & 1;
    const int lr = lane & 15, lk = lane >> 4;
    const int m0 = blockIdx.y * 64, n0 = blockIdx.x * 64;
    f32x4 acc[2][2] = {};

    for (int k0 = 0; k0 < K; k0 += 64) {
#pragma unroll
        for (int it = 0; it < 2; ++it) {
            int chunk = it * 256 + tid;          // 0..511
            int r = chunk >> 3, g = chunk & 7;
            int loff = r * 128 + ((g ^ (r & 7)) * 16);
            *reinterpret_cast<uint4*>(As + loff) =
                *reinterpret_cast<const uint4*>(&A[(size_t)(m0 + r) * K + k0 + g * 8]);
            *reinterpret_cast<uint4*>(Bs + loff) =
                *reinterpret_cast<const uint4*>(&Wt[(size_t)(n0 + r) * K + k0 + g * 8]);
        }
        __syncthreads();
#pragma unroll
        for (int kc = 0; kc < 2; ++kc) {
            int g = kc * 4 + lk;                 // 8-elem k-group within row
            bf16x8 af[2], bfr[2];
#pragma unroll
            for (int mi = 0; mi < 2; ++mi) {
                int r = wr * 32 + mi * 16 + lr;
                af[mi] = *reinterpret_cast<const bf16x8*>(As + r * 128 + ((g ^ (r & 7)) * 16));
            }
#pragma unroll
            for (int ni = 0; ni < 2; ++ni) {
                int r = wc * 32 + ni * 16 + lr;
                bfr[ni] = *reinterpret_cast<const bf16x8*>(Bs + r * 128 + ((g ^ (r & 7)) * 16));
            }
#pragma unroll
            for (int mi = 0; mi < 2; ++mi)
#pragma unroll
                for (int ni = 0; ni < 2; ++ni)
                    acc[mi][ni] = __builtin_amdgcn_mfma_f32_16x16x32_bf16(
                        af[mi], bfr[ni], acc[mi][ni], 0, 0, 0);
        }
        __syncthreads();
    }

#pragma unroll
    for (int mi = 0; mi < 2; ++mi)
#pragma unroll
    for (int ni = 0; ni < 2; ++ni)
#pragma unroll
    for (int j = 0; j < 4; ++j) {
        int row = m0 + wr * 32 + mi * 16 + (lane >> 4) * 4 + j;
        int col = n0 + wc * 32 + ni * 16 + (lane & 15);
        float v = acc[mi][ni][j] + bias[col];
        if (MODE == 2) {
            ((__hip_bfloat16*)Cout)[(size_t)row * N + col] =
                __float2bfloat16(0.5f * v * (1.f + erff(v * 0.70710678118654752f)));
        } else {
            int bb2 = row / KSEL, ss = row % KSEL;
            int pi = selidx[row];
            v += pos[(size_t)(1 + pi) * DIM + col];
            ((float*)Cout)[((size_t)bb2 * SEQ + 1 + ss) * DIM + col] = v;
        }
    }
}

// ---------------- qkv GEMM: N=576; cols<384 -> qk; cols>=384 -> Vt^T --------
__global__ __launch_bounds__(256) void gemm_qkv(const __hip_bfloat16* __restrict__ A,
                                                const __hip_bfloat16* __restrict__ Wt,
                                                const float* __restrict__ bias,
                                                __hip_bfloat16* __restrict__ qk,
                                                __hip_bfloat16* __restrict__ Vt)
{
    __shared__ __align__(16) char As[8192];
    __shared__ __align__(16) char Bs[8192];
    const int tid = threadIdx.x;
    const int lane = tid & 63, wid = tid >> 6;
    const int wr = wid >> 1, wc = wid & 1;
    const int lr = lane & 15, lk = lane >> 4;
    const int m0 = blockIdx.y * 64, n0 = blockIdx.x * 64;
    const int K = DIM;
    f32x4 acc[2][2] = {};

    for (int k0 = 0; k0 < K; k0 += 64) {
#pragma unroll
        for (int it = 0; it < 2; ++it) {
            int chunk = it * 256 + tid;
            int r = chunk >> 3, g = chunk & 7;
            int loff = r * 128 + ((g ^ (r & 7)) * 16);
            *reinterpret_cast<uint4*>(As + loff) =
                *reinterpret_cast<const uint4*>(&A[(size_t)(m0 + r) * K + k0 + g * 8]);
            *reinterpret_cast<uint4*>(Bs + loff) =
                *reinterpret_cast<const uint4*>(&Wt[(size_t)(n0 + r) * K + k0 + g * 8]);
        }
        __syncthreads();
#pragma unroll
        for (int kc = 0; kc < 2; ++kc) {
            int g = kc * 4 + lk;
            bf16x8 af[2], bfr[2];
#pragma unroll
            for (int mi = 0; mi < 2; ++mi) {
                int r = wr * 32 + mi * 16 + lr;
                af[mi] = *reinterpret_cast<const bf16x8*>(As + r * 128 + ((g ^ (r & 7)) * 16));
            }
#pragma unroll
            for (int ni = 0; ni < 2; ++ni) {
                int r = wc * 32 + ni * 16 + lr;
                bfr[ni] = *reinterpret_cast<const bf16x8*>(Bs + r * 128 + ((g ^ (r & 7)) * 16));
            }
#pragma unroll
            for (int mi = 0; mi < 2; ++mi)
#pragma unroll
                for (int ni = 0; ni < 2; ++ni)
                    acc[mi][ni] = __builtin_amdgcn_mfma_f32_16x16x32_bf16(
                        af[mi], bfr[ni], acc[mi][ni], 0, 0, 0);
        }
        __syncthreads();
    }

#pragma unroll
    for (int mi = 0; mi < 2; ++mi)
#pragma unroll
    for (int ni = 0; ni < 2; ++ni)
#pragma unroll
    for (int j = 0; j < 4; ++j) {
        int row = m0 + wr * 32 + mi * 16 + (lane >> 4) * 4 + j;
        int col = n0 + wc * 32 + ni * 16 + (lane & 15);
        float v = acc[mi][ni][j] + bias[col];
        if (col < 384) {
            qk[(size_t)row * 384 + col] = __float2bfloat16(v);
        } else {
            int c = col - 384;
            int b = row / SEQ, s = row - b * SEQ;
            Vt[((size_t)(b * 3 + (c >> 6)) * 64 + (c & 63)) * 160 + s] = __float2bfloat16(v);
        }
    }
}

// ---------------- fused attention + proj + bias + residual + ln2 (R5) -------
__global__ __launch_bounds__(256) void attnproj_kernel(const __hip_bfloat16* __restrict__ qk,
                                                       const __hip_bfloat16* __restrict__ Vt,
                                                       const __hip_bfloat16* __restrict__ Wp,
                                                       const float* __restrict__ pbias,
                                                       float* __restrict__ h,
                                                       const float* __restrict__ ls,
                                                       const float* __restrict__ lb,
                                                       __hip_bfloat16* __restrict__ y)
{
    const int b = blockIdx.y, qt = blockIdx.x;
    const int tid = threadIdx.x;
    const int w = tid >> 6, lane = tid & 63;
    const int lr = lane & 15, lg = lane >> 4;
    __shared__ __hip_bfloat16 Ps[3][32][168];
    __shared__ __hip_bfloat16 Ot[32][200];
    __shared__ float redsum[4][32];
    __shared__ float redsq[4][32];

    const size_t qbase = (size_t)b * SEQ * 384;
    const int q0 = qt * 32;

    if (w < 3) {
        const int hh = w;
        bf16x8 aq[2][2];
#pragma unroll
        for (int mi = 0; mi < 2; ++mi)
#pragma unroll
            for (int ks = 0; ks < 2; ++ks)
                aq[mi][ks] = *reinterpret_cast<const bf16x8*>(
                    &qk[qbase + (size_t)(q0 + mi * 16 + lr) * 384 + hh * 64 + ks * 32 + lg * 8]);
        f32x4 sc[2][10];
#pragma unroll
        for (int mi = 0; mi < 2; ++mi)
#pragma unroll
            for (int nf = 0; nf < 10; ++nf) sc[mi][nf] = (f32x4){0.f, 0.f, 0.f, 0.f};
#pragma unroll
        for (int nf = 0; nf < 10; ++nf) {
            int key = nf * 16 + lr;
#pragma unroll
            for (int ks = 0; ks < 2; ++ks) {
                bf16x8 bk = *reinterpret_cast<const bf16x8*>(
                    &qk[qbase + (size_t)key * 384 + 192 + hh * 64 + ks * 32 + lg * 8]);
#pragma unroll
                for (int mi = 0; mi < 2; ++mi)
                    sc[mi][nf] = __builtin_amdgcn_mfma_f32_16x16x32_bf16(
                        aq[mi][ks], bk, sc[mi][nf], 0, 0, 0);
            }
        }
#pragma unroll
        for (int mi = 0; mi < 2; ++mi) {
            float mx[4] = {-1e30f, -1e30f, -1e30f, -1e30f};
#pragma unroll
            for (int nf = 0; nf < 10; ++nf) {
                bool valid = nf * 16 + lr < SEQ;
#pragma unroll
                for (int j = 0; j < 4; ++j) {
                    float v = valid ? sc[mi][nf][j] * 0.125f : -1e30f;
                    sc[mi][nf][j] = v;
                    mx[j] = fmaxf(mx[j], v);
                }
            }
#pragma unroll
            for (int j = 0; j < 4; ++j)
                for (int off = 1; off < 16; off <<= 1)
                    mx[j] = fmaxf(mx[j], __shfl_xor(mx[j], off));
            float sm[4] = {0.f, 0.f, 0.f, 0.f};
#pragma unroll
            for (int nf = 0; nf < 10; ++nf)
#pragma unroll
                for (int j = 0; j < 4; ++j) {
                    float p = __expf(sc[mi][nf][j] - mx[j]);
                    sc[mi][nf][j] = p;
                    sm[j] += p;
                }
#pragma unroll
            for (int j = 0; j < 4; ++j) {
                for (int off = 1; off < 16; off <<= 1) sm[j] += __shfl_xor(sm[j], off);
                sm[j] = 1.f / sm[j];
            }
#pragma unroll
            for (int nf = 0; nf < 10; ++nf) {
                int key = nf * 16 + lr;
#pragma unroll
                for (int j = 0; j < 4; ++j)
                    Ps[hh][mi * 16 + lg * 4 + j][key] = __float2bfloat16(sc[mi][nf][j] * sm[j]);
            }
        }
        const __hip_bfloat16* vtb = &Vt[(size_t)(b * 3 + hh) * 64 * 160];
        f32x4 oacc[2][4];
#pragma unroll
        for (int mi = 0; mi < 2; ++mi)
#pragma unroll
            for (int nf = 0; nf < 4; ++nf) oacc[mi][nf] = (f32x4){0.f, 0.f, 0.f, 0.f};
#pragma unroll
        for (int ks = 0; ks < 5; ++ks) {
            bf16x8 ap[2];
            ap[0] = *reinterpret_cast<const bf16x8*>(&Ps[hh][lr][ks * 32 + lg * 8]);
            ap[1] = *reinterpret_cast<const bf16x8*>(&Ps[hh][16 + lr][ks * 32 + lg * 8]);
#pragma unroll
            for (int nf = 0; nf < 4; ++nf) {
                bf16x8 bv = *reinterpret_cast<const bf16x8*>(
                    &vtb[(size_t)(nf * 16 + lr) * 160 + ks * 32 + lg * 8]);
#pragma unroll
                for (int mi = 0; mi < 2; ++mi)
                    oacc[mi][nf] = __builtin_amdgcn_mfma_f32_16x16x32_bf16(
                        ap[mi], bv, oacc[mi][nf], 0, 0, 0);
            }
        }
#pragma unroll
        for (int mi = 0; mi < 2; ++mi)
#pragma unroll
            for (int nf = 0; nf < 4; ++nf)
#pragma unroll
                for (int j = 0; j < 4; ++j)
                    Ot[mi * 16 + lg * 4 + j][hh * 64 + nf * 16 + lr] =
                        __float2bfloat16(oacc[mi][nf][j]);
    }
    __syncthreads();

    f32x4 pacc[2][3];
#pragma unroll
    for (int mi = 0; mi < 2; ++mi)
#pragma unroll
        for (int nf = 0; nf < 3; ++nf) pacc[mi][nf] = (f32x4){0.f, 0.f, 0.f, 0.f};
#pragma unroll
    for (int kk = 0; kk < 6; ++kk) {
        bf16x8 af[2];
        af[0] = *reinterpret_cast<const bf16x8*>(&Ot[lr][kk * 32 + lg * 8]);
        af[1] = *reinterpret_cast<const bf16x8*>(&Ot[16 + lr][kk * 32 + lg * 8]);
#pragma unroll
        for (int nf = 0; nf < 3; ++nf) {
            int ncol = w * 48 + nf * 16 + lr;
            bf16x8 bw = *reinterpret_cast<const bf16x8*>(&Wp[(size_t)ncol * 192 + kk * 32 + lg * 8]);
#pragma unroll
            for (int mi = 0; mi < 2; ++mi)
                pacc[mi][nf] = __builtin_amdgcn_mfma_f32_16x16x32_bf16(
                    af[mi], bw, pacc[mi][nf], 0, 0, 0);
        }
    }
    float v[2][3][4];
    float psum[2][4] = {}, psq[2][4] = {};
#pragma unroll
    for (int mi = 0; mi < 2; ++mi)
#pragma unroll
    for (int nf = 0; nf < 3; ++nf) {
        int col = w * 48 + nf * 16 + lr;
        float bcol = pbias[col];
#pragma unroll
        for (int j = 0; j < 4; ++j) {
            int q = q0 + mi * 16 + lg * 4 + j;
            float res = (q < SEQ) ? h[((size_t)b * SEQ + q) * DIM + col] : 0.f;
            float t = pacc[mi][nf][j] + bcol + res;
            v[mi][nf][j] = t;
            psum[mi][j] += t;
            psq[mi][j] += t * t;
        }
    }
#pragma unroll
    for (int mi = 0; mi < 2; ++mi)
#pragma unroll
        for (int j = 0; j < 4; ++j) {
            for (int off = 1; off < 16; off <<= 1) {
                psum[mi][j] += __shfl_xor(psum[mi][j], off);
                psq[mi][j]  += __shfl_xor(psq[mi][j], off);
            }
            redsum[w][mi * 16 + lg * 4 + j] = psum[mi][j];
            redsq[w][mi * 16 + lg * 4 + j]  = psq[mi][j];
        }
    __syncthreads();
#pragma unroll
    for (int mi = 0; mi < 2; ++mi) {
#pragma unroll
        for (int j = 0; j < 4; ++j) {
            int r = mi * 16 + lg * 4 + j;
            int q = q0 + r;
            if (q >= SEQ) continue;
            float tsum = redsum[0][r] + redsum[1][r] + redsum[2][r] + redsum[3][r];
            float tsq  = redsq[0][r]  + redsq[1][r]  + redsq[2][r]  + redsq[3][r];
            float mean = tsum * (1.f / 192.f);
            float var  = tsq * (1.f / 192.f) - mean * mean;
            float rs = rsqrtf(var + 1e-6f);
#pragma unroll
            for (int nf = 0; nf < 3; ++nf) {
                int col = w * 48 + nf * 16 + lr;
                float t = v[mi][nf][j];
                h[((size_t)b * SEQ + q) * DIM + col] = t;
                y[((size_t)b * SEQ + q) * DIM + col] =
                    __float2bfloat16((t - mean) * rs * ls[col] + lb[col]);
            }
        }
    }
}

// ---------------- fc2 + bias + residual + LN (round-5 version) --------------
template <bool DO_LN>
__global__ __launch_bounds__(256) void gemm_res_ln(const __hip_bfloat16* __restrict__ A,
                                                   const __hip_bfloat16* __restrict__ Wt,
                                                   const float* __restrict__ bias,
                                                   float* __restrict__ h,
                                                   const float* __restrict__ ls,
                                                   const float* __restrict__ lb,
                                                   __hip_bfloat16* __restrict__ y,
                                                   int K)
{
    __shared__ __align__(16) char As[8192];    // 64 x 64 bf16 swizzled
    __shared__ __align__(16) char Bs[24576];   // 192 x 64 bf16 swizzled
    const int tid = threadIdx.x;
    const int lane = tid & 63, w = tid >> 6;
    const int lr = lane & 15, lg = lane >> 4;
    const int m0 = blockIdx.x * 64;
    f32x4 acc[12] = {};

    for (int k0 = 0; k0 < K; k0 += 64) {
        {
            int chunk = tid;
#pragma unroll
            for (int it = 0; it < 2; ++it, chunk += 256) {
                int r = chunk >> 3, g = chunk & 7;
                *reinterpret_cast<uint4*>(As + r * 128 + ((g ^ (r & 7)) * 16)) =
                    *reinterpret_cast<const uint4*>(&A[(size_t)(m0 + r) * K + k0 + g * 8]);
            }
        }
        {
            int chunk = tid;
#pragma unroll
            for (int it = 0; it < 6; ++it, chunk += 256) {
                int r = chunk >> 3, g = chunk & 7;
                *reinterpret_cast<uint4*>(Bs + r * 128 + ((g ^ (r & 7)) * 16)) =
                    *reinterpret_cast<const uint4*>(&Wt[(size_t)r * K + k0 + g * 8]);
            }
        }
        __syncthreads();
#pragma unroll
        for (int kc = 0; kc < 2; ++kc) {
            int g = kc * 4 + lg;
            int ar = w * 16 + lr;
            bf16x8 af = *reinterpret_cast<const bf16x8*>(As + ar * 128 + ((g ^ (ar & 7)) * 16));
#pragma unroll
            for (int nf = 0; nf < 12; ++nf) {
                int br = nf * 16 + lr;
                bf16x8 bfv = *reinterpret_cast<const bf16x8*>(Bs + br * 128 + ((g ^ (br & 7)) * 16));
                acc[nf] = __builtin_amdgcn_mfma_f32_16x16x32_bf16(af, bfv, acc[nf], 0, 0, 0);
            }
        }
        __syncthreads();
    }

    float v[12][4];
    float sum[4] = {0.f, 0.f, 0.f, 0.f};
#pragma unroll
    for (int nf = 0; nf < 12; ++nf) {
        int col = nf * 16 + lr;
#pragma unroll
        for (int j = 0; j < 4; ++j) {
            int row = m0 + w * 16 + lg * 4 + j;
            float t = acc[nf][j] + bias[col] + h[(size_t)row * DIM + col];
            v[nf][j] = t;
            h[(size_t)row * DIM + col] = t;
            sum[j] += t;
        }
    }
    if (DO_LN) {
#pragma unroll
        for (int j = 0; j < 4; ++j)
            for (int off = 1; off < 16; off <<= 1) sum[j] += __shfl_xor(sum[j], off);
        float mean[4], sq[4] = {0.f, 0.f, 0.f, 0.f};
#pragma unroll
        for (int j = 0; j < 4; ++j) mean[j] = sum[j] * (1.f / 192.f);
#pragma unroll
        for (int nf = 0; nf < 12; ++nf)
#pragma unroll
            for (int j = 0; j < 4; ++j) {
                float d = v[nf][j] - mean[j];
                sq[j] += d * d;
            }
#pragma unroll
        for (int j = 0; j < 4; ++j) {
            for (int off = 1; off < 16; off <<= 1) sq[j] += __shfl_xor(sq[j], off);
            sq[j] = rsqrtf(sq[j] * (1.f / 192.f) + 1e-6f);
        }
#pragma unroll
        for (int nf = 0; nf < 12; ++nf) {
            int col = nf * 16 + lr;
            float sc = ls[col], bc = lb[col];
#pragma unroll
            for (int j = 0; j < 4; ++j) {
                int row = m0 + w * 16 + lg * 4 + j;
                y[(size_t)row * DIM + col] =
                    __float2bfloat16((v[nf][j] - mean[j]) * sq[j] * sc + bc);
            }
        }
    }
}

// ---------------- head: final LN of cls + (64,192)@(192,1000) ---------------
__global__ __launch_bounds__(256) void head_kernel(const float* __restrict__ h,
                                                   const float* __restrict__ nfs,
                                                   const float* __restrict__ nfb,
                                                   const float* __restrict__ hw,
                                                   const float* __restrict__ hb,
                                                   float* __restrict__ out)
{
    int b = blockIdx.x, t = threadIdx.x;
    __shared__ float y[DIM];
    __shared__ float red[4];
    float x = (t < DIM) ? h[(size_t)b * SEQ * DIM + t] : 0.f;
    float sum = x;
    for (int off = 32; off; off >>= 1) sum += __shfl_xor(sum, off);
    if ((t & 63) == 0) red[t >> 6] = sum;
    __syncthreads();
    float mean = (red[0] + red[1] + red[2] + red[3]) * (1.f / 192.f);
    __syncthreads();
    float d = (t < DIM) ? (x - mean) : 0.f;
    float v = d * d;
    for (int off = 32; off; off >>= 1) v += __shfl_xor(v, off);
    if ((t & 63) == 0) red[t >> 6] = v;
    __syncthreads();
    float var = (red[0] + red[1] + red[2] + red[3]) * (1.f / 192.f);
    float rs = rsqrtf(var + 1e-6f);
    if (t < DIM) y[t] = d * rs * nfs[t] + nfb[t];
    __syncthreads();
    for (int n = t; n < 1000; n += 256) {
        float acc = hb[n];
#pragma unroll 8
        for (int k = 0; k < DIM; ++k)
            acc = fmaf(y[k], hw[(size_t)k * 1000 + n], acc);
        out[(size_t)b * 1000 + n] = acc;
    }
}

// ---------------------------------------------------------------------------
extern "C" void kernel_launch(void* const* d_in, const int* in_sizes, int n_in,
                              void* d_out, int out_size, void* d_ws, size_t ws_size,
                              hipStream_t stream)
{
    const float* magno  = (const float*)d_in[0];
    const float* line   = (const float*)d_in[1];
    const float* conv_w = (const float*)d_in[2];
    const float* conv_b = (const float*)d_in[3];
    const float* pos    = (const float*)d_in[4];
    const float* cls    = (const float*)d_in[5];
    const float* ln1_s  = (const float*)d_in[6];
    const float* ln1_b  = (const float*)d_in[7];
    const float* qkv_w  = (const float*)d_in[8];
    const float* qkv_b  = (const float*)d_in[9];
    const float* proj_w = (const float*)d_in[10];
    const float* proj_b = (const float*)d_in[11];
    const float* ln2_s  = (const float*)d_in[12];
    const float* ln2_b  = (const float*)d_in[13];
    const float* fc1_w  = (const float*)d_in[14];
    const float* fc1_b  = (const float*)d_in[15];
    const float* fc2_w  = (const float*)d_in[16];
    const float* fc2_b  = (const float*)d_in[17];
    const float* normf_s = (const float*)d_in[18];
    const float* normf_b = (const float*)d_in[19];
    const float* head_w = (const float*)d_in[20];
    const float* head_b = (const float*)d_in[21];
    float* out = (float*)d_out;
    (void)in_sizes; (void)n_in; (void)out_size; (void)ws_size;

    // workspace layout (bytes)
    char* ws = (char*)d_ws;
    int*            idx     = (int*)            (ws + 0);         //    36864 (pad)
    float*          h       = (float*)          (ws + 147456);    //  7127040
    __hip_bfloat16* y       = (__hip_bfloat16*) (ws + 7274496);   //  3563520
    __hip_bfloat16* qk      = (__hip_bfloat16*) (ws + 10838016);  //  7127040
    __hip_bfloat16* Vt      = (__hip_bfloat16*) (ws + 17965056);  //  3932160
    __hip_bfloat16* tbuf    = (__hip_bfloat16*) (ws + 21897216);  // 14254080
    __hip_bfloat16* wt_qkv  = (__hip_bfloat16*) (ws + 36151296);  //  2654208
    __hip_bfloat16* wt_proj = (__hip_bfloat16*) (ws + 38805504);  //   884736
    __hip_bfloat16* wt_fc1  = (__hip_bfloat16*) (ws + 39690240);  //  3538944
    __hip_bfloat16* wt_fc2  = (__hip_bfloat16*) (ws + 43229184);  //  3538944
    float*          scoresbuf = (float*)qk;             // alias (used before qk)
    __hip_bfloat16* convT     = y;                      // alias (used before y)
    __hip_bfloat16* selp      = tbuf;                   // alias

    // ---- prep: weights -> bf16 [N][K] (one kernel); zero Vt pads once ----
    hipMemsetAsync(Vt, 0, 3932160, stream);
    prep_weights<<<5328, 256, 0, stream>>>(qkv_w, proj_w, fc1_w, fc2_w, conv_w,
                                           wt_qkv, wt_proj, wt_fc1, wt_fc2, convT);

    // ---- patch selection + embed ----
    scores_kernel<<<Bsz * NPATCH / 4, 256, 0, stream>>>(line, scoresbuf);
    topk_kernel<<<Bsz, 256, 0, stream>>>(scoresbuf, idx);
    gather_kernel<<<Bsz * KSEL, 256, 0, stream>>>(magno, idx, selp);
    cls_kernel<<<Bsz, DIM, 0, stream>>>(cls, pos, h);
    gemm_bf16<3><<<dim3(3, 144), 256, 0, stream>>>(selp, convT, conv_b, h,
                                                   9216, DIM, 768, idx, pos);

    const int ntok = Bsz * SEQ;              // 9280 = 145*64
    ln_kernel<<<ntok / 4, 256, 0, stream>>>(h, ln1_s, ln1_b, y, ntok);
    for (int l = 0; l < 12; ++l) {
        gemm_qkv<<<dim3(9, 145), 256, 0, stream>>>(y, wt_qkv + (size_t)l * 576 * DIM,
                                                   qkv_b + l * 576, qk, Vt);
        attnproj_kernel<<<dim3(5, Bsz), 256, 0, stream>>>(qk, Vt,
                                                          wt_proj + (size_t)l * DIM * DIM,
                                                          proj_b + l * DIM, h,
                                                          ln2_s + l * DIM, ln2_b + l * DIM, y);
        gemm_bf16<2><<<dim3(12, 145), 256, 0, stream>>>(y, wt_fc1 + (size_t)l * HIDN * DIM,
                                                        fc1_b + l * HIDN, tbuf,
                                                        ntok, HIDN, DIM, nullptr, nullptr);
        if (l < 11)
            gemm_res_ln<true><<<145, 256, 0, stream>>>(
                tbuf, wt_fc2 + (size_t)l * DIM * HIDN, fc2_b + l * DIM, h,
                ln1_s + (l + 1) * DIM, ln1_b + (l + 1) * DIM, y, HIDN);
        else
            gemm_res_ln<false><<<145, 256, 0, stream>>>(
                tbuf, wt_fc2 + (size_t)l * DIM * HIDN, fc2_b + l * DIM, h,
                nullptr, nullptr, y, HIDN);
    }
    head_kernel<<<Bsz, 256, 0, stream>>>(h, normf_s, normf_b, head_w, head_b, out);
}